// Round 11
// baseline (393.722 us; speedup 1.0000x reference)
//
#include <hip/hip_runtime.h>
#include <math.h>
#include <type_traits>

#define N_NODES 50000
#define N_EDGES 800000
#define DIM 96
#define BCH 12                    // 16-byte chunks per bf16 row (96 shorts)
#define SCAN_BLK 256
#define NBLK ((N_NODES + SCAN_BLK - 1) / SCAN_BLK)    // 196
#define NPB 21                    // nodes per gather block (21*12 = 252 active threads)
#define NBG ((N_NODES + NPB - 1) / NPB)               // 2381 gather blocks
#define CAP 768                   // LDS entry buffer (int2) per tile
#define NBINS 256                 // degree bins (max deg ~45 for Poisson(16))
#define R1_ROWS 24
#define R1_BLOCKS ((NBG + R1_ROWS - 1) / R1_ROWS)     // 100

typedef short v8s __attribute__((ext_vector_type(8)));   // 8 bf16 = 4 VGPRs
typedef float v4f __attribute__((ext_vector_type(4)));   // MFMA accumulator

// ---- bf16 helpers (RNE) ----
__device__ __forceinline__ unsigned short f2bf(float f) {
    unsigned int u = __float_as_uint(f);
    u += 0x7FFFu + ((u >> 16) & 1u);
    return (unsigned short)(u >> 16);
}
__device__ __forceinline__ unsigned int pack2bf(float lo, float hi) {
    return (unsigned int)f2bf(lo) | ((unsigned int)f2bf(hi) << 16);
}
__device__ __forceinline__ float bflo(unsigned int u) { return __uint_as_float(u << 16); }
__device__ __forceinline__ float bfhi(unsigned int u) { return __uint_as_float(u & 0xFFFF0000u); }

__device__ __forceinline__ float fast_tanh(float x) {
    float ax = fabsf(x);
    float t = __expf(-2.0f * ax);
    float r = (1.0f - t) / (1.0f + t);
    return copysignf(r, x);
}

__device__ __forceinline__ void acc8(float* a, uint4 v, float f) {
    a[0] += bflo(v.x) * f; a[1] += bfhi(v.x) * f;
    a[2] += bflo(v.y) * f; a[3] += bfhi(v.y) * f;
    a[4] += bflo(v.z) * f; a[5] += bfhi(v.z) * f;
    a[6] += bflo(v.w) * f; a[7] += bfhi(v.w) * f;
}

union U4S8 { uint4 u; v8s s; };

// ---------------- linked-list CSR build (degree-sorted placement) ----------------

__global__ void link_edges(const int* __restrict__ dst, int* __restrict__ head,
                           int* __restrict__ nxt) {
    int e = blockIdx.x * blockDim.x + threadIdx.x;
    if (e >= N_EDGES) return;
    int old = atomicExch(&head[dst[e]], e);
    nxt[e] = old;
}

// walk list: deg + norm; LDS degree histogram -> global bins
__global__ void walk_count_hist(const int* __restrict__ head, const int* __restrict__ nxt,
                                int* __restrict__ deg, float* __restrict__ norm,
                                int* __restrict__ bins) {
    __shared__ int h[NBINS];
    int t = threadIdx.x;
    h[t] = 0;
    __syncthreads();
    int n = blockIdx.x * SCAN_BLK + t;
    if (n < N_NODES) {
        int cnt = 0;
        int p = head[n];
        while (p >= 0) { ++cnt; p = nxt[p]; }
        deg[n] = cnt;
        norm[n] = rsqrtf(fmaxf((float)cnt, 1.0f));
        atomicAdd(&h[min(cnt, NBINS - 1)], 1);
    }
    __syncthreads();
    if (h[t]) atomicAdd(&bins[t], h[t]);
}

// single block: exclusive scans of bin counts (node ranks) and count*deg (edge offsets)
__global__ void bin_scan(const int* __restrict__ bins, int* __restrict__ nodeStart,
                         int* __restrict__ edgeStart, int* __restrict__ binCursor) {
    __shared__ int a[NBINS], b[NBINS];
    int t = threadIdx.x;
    int c = bins[t];
    int cw = c * t;
    a[t] = c; b[t] = cw;
    __syncthreads();
    for (int off = 1; off < NBINS; off <<= 1) {
        int u = (t >= off) ? a[t - off] : 0;
        int v = (t >= off) ? b[t - off] : 0;
        __syncthreads();
        a[t] += u; b[t] += v;
        __syncthreads();
    }
    nodeStart[t] = a[t] - c;
    edgeStart[t] = b[t] - cw;
    binCursor[t] = 0;
}

// rank + closed-form edge offset per node; perm + sorted offs
__global__ void rank_assign(const int* __restrict__ deg, const int* __restrict__ nodeStart,
                            const int* __restrict__ edgeStart, int* __restrict__ binCursor,
                            int* __restrict__ perm, int* __restrict__ eoffs,
                            int* __restrict__ soffs) {
    int n = blockIdx.x * SCAN_BLK + threadIdx.x;
    if (n < N_NODES) {
        int d = deg[n];
        int w = atomicAdd(&binCursor[d], 1);
        int r = nodeStart[d] + w;
        int eo = edgeStart[d] + w * d;
        perm[r] = n;
        eoffs[n] = eo;
        soffs[r] = eo;
    }
    if (n == 0) soffs[N_NODES] = N_EDGES;
}

// walk list, write entries sequentially into the node's sorted segment
__global__ void compact(const int* __restrict__ head, const int* __restrict__ nxt,
                        const int* __restrict__ src, const float* __restrict__ factor,
                        const int* __restrict__ eoffs, int2* __restrict__ entries) {
    int n = blockIdx.x * SCAN_BLK + threadIdx.x;
    if (n >= N_NODES) return;
    int o = eoffs[n];
    int p = head[n];
    while (p >= 0) {
        entries[o++] = make_int2(src[p], __float_as_int(factor[p]));
        p = nxt[p];
    }
}

// ---------------- W pre-swizzle: B-fragments for mfma_f32_16x16x32_bf16 ----------------

__global__ void swizzle_W(const float* __restrict__ W, uint4* __restrict__ bsw) {
    int idx = blockIdx.x * blockDim.x + threadIdx.x;
    if (idx >= 18 * 64) return;
    int t = idx >> 6, lane = idx & 63;
    int kt = t / 6, jt = t % 6;
    int quad = lane >> 4, l16 = lane & 15;
    const float4* wp = (const float4*)(W + (size_t)(jt * 16 + l16) * DIM + kt * 32 + quad * 8);
    float4 w0 = wp[0], w1 = wp[1];
    bsw[idx] = make_uint4(pack2bf(w0.x, w0.y), pack2bf(w0.z, w0.w),
                          pack2bf(w1.x, w1.y), pack2bf(w1.z, w1.w));
}

// ---------------- MFMA GEMM:  out[n][j] = bf16((X@W^T + b)[n][j] * norm[n]) ----------------

#define TILE_SH 104   // shorts per LDS tile row

template <typename T>
__global__ __launch_bounds__(256) void gemm_mfma(const T* __restrict__ X,
                                                 const uint4* __restrict__ bsw,
                                                 const float* __restrict__ bias,
                                                 const float* __restrict__ norm,
                                                 unsigned short* __restrict__ out) {
    __shared__ unsigned short tile[4][16 * TILE_SH];   // 13.3 KB
    int tid = threadIdx.x;
    int wave = tid >> 6, lane = tid & 63;
    int quad = lane >> 4, l16 = lane & 15;
    int n0 = blockIdx.x * 64 + wave * 16;
    int rowc = min(n0 + l16, N_NODES - 1);

    uint4 bfr[18];
#pragma unroll
    for (int t = 0; t < 18; ++t) bfr[t] = bsw[t * 64 + lane];

    v4f acc[6];
#pragma unroll
    for (int jt = 0; jt < 6; ++jt) acc[jt] = (v4f)(0.0f);

#pragma unroll
    for (int kt = 0; kt < 3; ++kt) {
        U4S8 a;
        if constexpr (std::is_same_v<T, float>) {
            const float4* xp = (const float4*)(X + (size_t)rowc * DIM + kt * 32 + quad * 8);
            float4 x0 = xp[0], x1 = xp[1];
            a.u = make_uint4(pack2bf(x0.x, x0.y), pack2bf(x0.z, x0.w),
                             pack2bf(x1.x, x1.y), pack2bf(x1.z, x1.w));
        } else {
            a.u = *(const uint4*)(X + (size_t)rowc * DIM + kt * 32 + quad * 8);
        }
#pragma unroll
        for (int jt = 0; jt < 6; ++jt) {
            U4S8 bb; bb.u = bfr[kt * 6 + jt];
            acc[jt] = __builtin_amdgcn_mfma_f32_16x16x32_bf16(a.s, bb.s, acc[jt], 0, 0, 0);
        }
    }

    float nm[4];
#pragma unroll
    for (int r = 0; r < 4; ++r) nm[r] = norm[min(n0 + quad * 4 + r, N_NODES - 1)];
#pragma unroll
    for (int jt = 0; jt < 6; ++jt) {
        float bj = bias[jt * 16 + l16];
#pragma unroll
        for (int r = 0; r < 4; ++r) {
            float v = (acc[jt][r] + bj) * nm[r];
            tile[wave][(quad * 4 + r) * TILE_SH + jt * 16 + l16] = f2bf(v);
        }
    }
    __builtin_amdgcn_s_waitcnt(0);   // drain lgkm before wave-local reads
#pragma unroll
    for (int i = 0; i < 3; ++i) {
        int chunk = lane + 64 * i;        // 0..191 = 16 rows x 12 uint4
        int rr = chunk / 12, cc = chunk - rr * 12;
        int gn = n0 + rr;
        if (gn < N_NODES) {
            uint4 v = *(uint4*)&tile[wave][rr * TILE_SH + cc * 8];
            *(uint4*)(out + (size_t)gn * DIM + cc * 8) = v;
        }
    }
}

// ---------------- gather aggregation: degree-sorted ranks, LDS entries, x4 ----------------
// Block = 21 sorted-ranks x 12 chunks. Edge ranges contiguous in rank order;
// degrees within a block near-uniform -> minimal exec-mask divergence.

template <bool DO_TANH, bool POOL>
__global__ void gather_agg_bf16(const unsigned short* __restrict__ feat,
                                const int* __restrict__ soffs,
                                const int* __restrict__ perm,
                                const int2* __restrict__ entries,
                                unsigned short* __restrict__ out,
                                float* __restrict__ partials) {
    __shared__ int2 ents[CAP];       // 6 KB
    __shared__ float pool[DIM];
    __shared__ int sh_base, sh_cnt;
    int tid = threadIdx.x;
    int r0 = blockIdx.x * NPB;
    int r1 = min(r0 + NPB, N_NODES);
    if (POOL && tid < DIM) pool[tid] = 0.f;
    if (tid == 0) { sh_base = soffs[r0]; sh_cnt = soffs[r1] - sh_base; }
    __syncthreads();
    int base = sh_base, cnt = sh_cnt;

    int nl = tid / BCH;
    int c  = tid - nl * BCH;
    int rk = r0 + nl;
    bool active = (tid < NPB * BCH) && (rk < N_NODES);
    int lb = 0, le = 0;
    if (active) { lb = soffs[rk] - base; le = soffs[rk + 1] - base; }

    float a0[8], a1[8];
#pragma unroll
    for (int i = 0; i < 8; ++i) { a0[i] = 0.f; a1[i] = 0.f; }

    for (int tb = 0; tb < cnt; tb += CAP) {
        int tcnt = min(cnt - tb, CAP);
        if (tb) __syncthreads();
        for (int i = tid; i < tcnt; i += 256) ents[i] = entries[base + tb + i];
        __syncthreads();
        int s = max(lb - tb, 0), e = min(le - tb, tcnt);
        int p = s;
        for (; p + 3 < e; p += 4) {
            int2 e0 = ents[p], e1 = ents[p + 1], e2 = ents[p + 2], e3 = ents[p + 3];
            uint4 v0 = *((const uint4*)(feat + (size_t)e0.x * DIM) + c);
            uint4 v1 = *((const uint4*)(feat + (size_t)e1.x * DIM) + c);
            uint4 v2 = *((const uint4*)(feat + (size_t)e2.x * DIM) + c);
            uint4 v3 = *((const uint4*)(feat + (size_t)e3.x * DIM) + c);
            acc8(a0, v0, __int_as_float(e0.y));
            acc8(a1, v1, __int_as_float(e1.y));
            acc8(a0, v2, __int_as_float(e2.y));
            acc8(a1, v3, __int_as_float(e3.y));
        }
        for (; p < e; ++p) {
            int2 e0 = ents[p];
            uint4 v0 = *((const uint4*)(feat + (size_t)e0.x * DIM) + c);
            acc8(a0, v0, __int_as_float(e0.y));
        }
    }

#pragma unroll
    for (int i = 0; i < 8; ++i) a0[i] += a1[i];
    if (DO_TANH || POOL) {
#pragma unroll
        for (int i = 0; i < 8; ++i) a0[i] = fast_tanh(a0[i]);
    }
    if (!POOL) {
        if (active) {
            int n_out = perm[rk];
            uint4 o;
            o.x = pack2bf(a0[0], a0[1]);
            o.y = pack2bf(a0[2], a0[3]);
            o.z = pack2bf(a0[4], a0[5]);
            o.w = pack2bf(a0[6], a0[7]);
            ((uint4*)out)[n_out * BCH + c] = o;
        }
    } else {
        if (active) {
#pragma unroll
            for (int i = 0; i < 8; ++i) atomicAdd(&pool[c * 8 + i], a0[i]);
        }
        __syncthreads();
        if (tid < DIM) partials[(size_t)blockIdx.x * DIM + tid] = pool[tid];
    }
}

// ---------------- two-stage pooled reduce ----------------

__global__ void reduce_stage1(const float* __restrict__ poolpart, float* __restrict__ stage1) {
    __shared__ float pool[DIM];
    int b = blockIdx.x, t = threadIdx.x;
    if (t < DIM) pool[t] = 0.f;
    __syncthreads();
    const int base = b * R1_ROWS * DIM;
    float loc = 0.f;
    int lastc = -1;
    for (int i = t; i < R1_ROWS * DIM; i += 256) {
        int gi = base + i;
        if (gi < NBG * DIM) {
            int col = i % DIM;
            if (col != lastc) {
                if (lastc >= 0) atomicAdd(&pool[lastc], loc);
                lastc = col; loc = 0.f;
            }
            loc += poolpart[gi];
        }
    }
    if (lastc >= 0) atomicAdd(&pool[lastc], loc);
    __syncthreads();
    if (t < DIM) stage1[b * DIM + t] = pool[t];
}

__global__ void reduce_stage2(const float* __restrict__ stage1, float* __restrict__ out) {
    __shared__ float sm[960];
    int t = threadIdx.x;
    int col = t % DIM, slice = t / DIM;
    float s = 0.f;
    for (int k = slice; k < R1_BLOCKS; k += 10) s += stage1[k * DIM + col];
    sm[t] = s;
    __syncthreads();
    if (t < DIM) {
        float tot = 0.f;
#pragma unroll
        for (int i = 0; i < 10; ++i) tot += sm[i * DIM + t];
        out[t] = tanhf(tot * (1.0f / N_NODES));
    }
}

// ---------------- launch ----------------

extern "C" void kernel_launch(void* const* d_in, const int* in_sizes, int n_in,
                              void* d_out, int out_size, void* d_ws, size_t ws_size,
                              hipStream_t stream) {
    const float* inputs = (const float*)d_in[0];
    const float* W1     = (const float*)d_in[1];
    const float* b1     = (const float*)d_in[2];
    const float* W2     = (const float*)d_in[3];
    const float* b2     = (const float*)d_in[4];
    const float* factor = (const float*)d_in[5];
    const int*   src    = (const int*)d_in[6];
    const int*   dst    = (const int*)d_in[7];
    float* out = (float*)d_out;

    char* ws = (char*)d_ws;
    int*            head      = (int*)(ws + 0);              // 200 KB
    int*            nxt       = (int*)(ws + 262144);         // 3.2 MB
    int*            deg       = (int*)(ws + 3670016);        // 200 KB
    int*            soffs     = (int*)(ws + 3932160);        // 200 KB (+1)
    float*          norm      = (float*)(ws + 4194304);      // 200 KB
    int*            bins      = (int*)(ws + 4456448);        // 1 KB
    int*            nodeStart = (int*)(ws + 4457472);        // 1 KB
    int*            edgeStart = (int*)(ws + 4458496);        // 1 KB
    int*            binCursor = (int*)(ws + 4459520);        // 1 KB
    int2*           entries   = (int2*)(ws + 4718592);       // 6.4 MB
    unsigned short* bufA      = (unsigned short*)(ws + 11534336);  // 9.6 MB bf16 feat
    unsigned short* bufB      = (unsigned short*)(ws + 21364736);  // 9.6 MB bf16 feat
    float*          poolpart  = (float*)(ws + 31195136);     // 914 KB (NBG x 96)
    float*          stage1    = (float*)(ws + 32145536);     // 38.4 KB
    uint4*          bsw1      = (uint4*)(ws + 33554432);     // 18 KB W1 fragments
    uint4*          bsw2      = (uint4*)(ws + 33574912);     // 18 KB W2 fragments
    int*            perm      = (int*)(ws + 33595392);       // 200 KB
    int*            eoffs     = (int*)(ws + 33857536);       // 200 KB

    // W fragment pre-swizzle (independent of CSR build)
    swizzle_W<<<5, 256, 0, stream>>>(W1, bsw1);
    swizzle_W<<<5, 256, 0, stream>>>(W2, bsw2);

    // linked-list CSR build with degree-sorted placement
    hipMemsetAsync(head, 0xFF, N_NODES * sizeof(int), stream);
    hipMemsetAsync(bins, 0, NBINS * sizeof(int), stream);
    link_edges<<<(N_EDGES + 255) / 256, 256, 0, stream>>>(dst, head, nxt);
    walk_count_hist<<<NBLK, SCAN_BLK, 0, stream>>>(head, nxt, deg, norm, bins);
    bin_scan<<<1, NBINS, 0, stream>>>(bins, nodeStart, edgeStart, binCursor);
    rank_assign<<<NBLK, SCAN_BLK, 0, stream>>>(deg, nodeStart, edgeStart, binCursor,
                                               perm, eoffs, soffs);
    compact<<<NBLK, SCAN_BLK, 0, stream>>>(head, nxt, src, factor, eoffs, entries);

    const int GEMM_BLOCKS = (N_NODES + 63) / 64;   // 782

    // layer 1
    gemm_mfma<float><<<GEMM_BLOCKS, 256, 0, stream>>>(inputs, bsw1, b1, norm, bufA);
    gather_agg_bf16<true, false><<<NBG, 256, 0, stream>>>(bufA, soffs, perm, entries,
                                                          bufB, nullptr);

    // layer 2 (gather fuses tanh + column pooling, no feature write)
    gemm_mfma<unsigned short><<<GEMM_BLOCKS, 256, 0, stream>>>(bufB, bsw2, b2, norm, bufA);
    gather_agg_bf16<false, true><<<NBG, 256, 0, stream>>>(bufA, soffs, perm, entries,
                                                          nullptr, poolpart);

    // two-stage pooled reduce -> out
    reduce_stage1<<<R1_BLOCKS, 256, 0, stream>>>(poolpart, stage1);
    reduce_stage2<<<1, 960, 0, stream>>>(stage1, out);
}

// Round 12
// 267.261 us; speedup vs baseline: 1.4732x; 1.4732x over previous
//
#include <hip/hip_runtime.h>
#include <math.h>
#include <type_traits>

#define N_NODES 50000
#define N_EDGES 800000
#define DIM 96
#define BCH 12                    // 16-byte chunks per bf16 row (96 shorts)
#define SCAN_BLK 256
#define NBLK ((N_NODES + SCAN_BLK - 1) / SCAN_BLK)    // 196
#define NPB 21                    // nodes per gather block (21*12 = 252 active threads)
#define NBG ((N_NODES + NPB - 1) / NPB)               // 2381 gather blocks
#define CAP 768                   // LDS entry buffer (int2) per tile
#define NBINS 256                 // degree bins (max deg ~45 for Poisson(16))
#define R1_ROWS 24
#define R1_BLOCKS ((NBG + R1_ROWS - 1) / R1_ROWS)     // 100

typedef short v8s __attribute__((ext_vector_type(8)));   // 8 bf16 = 4 VGPRs
typedef float v4f __attribute__((ext_vector_type(4)));   // MFMA accumulator

// ---- bf16 helpers (RNE) ----
__device__ __forceinline__ unsigned short f2bf(float f) {
    unsigned int u = __float_as_uint(f);
    u += 0x7FFFu + ((u >> 16) & 1u);
    return (unsigned short)(u >> 16);
}
__device__ __forceinline__ unsigned int pack2bf(float lo, float hi) {
    return (unsigned int)f2bf(lo) | ((unsigned int)f2bf(hi) << 16);
}
__device__ __forceinline__ float bflo(unsigned int u) { return __uint_as_float(u << 16); }
__device__ __forceinline__ float bfhi(unsigned int u) { return __uint_as_float(u & 0xFFFF0000u); }

__device__ __forceinline__ float fast_tanh(float x) {
    float ax = fabsf(x);
    float t = __expf(-2.0f * ax);
    float r = (1.0f - t) / (1.0f + t);
    return copysignf(r, x);
}

__device__ __forceinline__ void acc8(float* a, uint4 v, float f) {
    a[0] += bflo(v.x) * f; a[1] += bfhi(v.x) * f;
    a[2] += bflo(v.y) * f; a[3] += bfhi(v.y) * f;
    a[4] += bflo(v.z) * f; a[5] += bfhi(v.z) * f;
    a[6] += bflo(v.w) * f; a[7] += bfhi(v.w) * f;
}

union U4S8 { uint4 u; v8s s; };

// ---------------- linked-list CSR build (degree-sorted placement) ----------------

__global__ void link_edges(const int* __restrict__ dst, int* __restrict__ head,
                           int* __restrict__ nxt) {
    int e = blockIdx.x * blockDim.x + threadIdx.x;
    if (e >= N_EDGES) return;
    int old = atomicExch(&head[dst[e]], e);
    nxt[e] = old;
}

// walk list: deg + norm; LDS degree histogram -> global bins
__global__ void walk_count_hist(const int* __restrict__ head, const int* __restrict__ nxt,
                                int* __restrict__ deg, float* __restrict__ norm,
                                int* __restrict__ bins) {
    __shared__ int h[NBINS];
    int t = threadIdx.x;
    h[t] = 0;
    __syncthreads();
    int n = blockIdx.x * SCAN_BLK + t;
    if (n < N_NODES) {
        int cnt = 0;
        int p = head[n];
        while (p >= 0) { ++cnt; p = nxt[p]; }
        deg[n] = cnt;
        norm[n] = rsqrtf(fmaxf((float)cnt, 1.0f));
        atomicAdd(&h[min(cnt, NBINS - 1)], 1);
    }
    __syncthreads();
    if (h[t]) atomicAdd(&bins[t], h[t]);
}

// single block: exclusive scans of bin counts (node ranks) and count*deg (edge offsets)
__global__ void bin_scan(const int* __restrict__ bins, int* __restrict__ nodeStart,
                         int* __restrict__ edgeStart, int* __restrict__ binCursor) {
    __shared__ int a[NBINS], b[NBINS];
    int t = threadIdx.x;
    int c = bins[t];
    int cw = c * t;
    a[t] = c; b[t] = cw;
    __syncthreads();
    for (int off = 1; off < NBINS; off <<= 1) {
        int u = (t >= off) ? a[t - off] : 0;
        int v = (t >= off) ? b[t - off] : 0;
        __syncthreads();
        a[t] += u; b[t] += v;
        __syncthreads();
    }
    nodeStart[t] = a[t] - c;
    edgeStart[t] = b[t] - cw;
    binCursor[t] = 0;
}

// rank + closed-form edge offset per node (hierarchical: LDS histogram,
// ONE global atomic per (block, non-empty bin), LDS cursors for intra-block rank)
__global__ void rank_assign(const int* __restrict__ deg, const int* __restrict__ nodeStart,
                            const int* __restrict__ edgeStart, int* __restrict__ binCursor,
                            int* __restrict__ perm, int* __restrict__ eoffs,
                            int* __restrict__ soffs) {
    __shared__ int h[NBINS], basec[NBINS], lc[NBINS];
    int t = threadIdx.x;
    h[t] = 0; lc[t] = 0;
    __syncthreads();
    int n = blockIdx.x * SCAN_BLK + t;
    int d = 0;
    if (n < N_NODES) {
        d = deg[n];
        atomicAdd(&h[d], 1);
    }
    __syncthreads();
    if (h[t] > 0) basec[t] = atomicAdd(&binCursor[t], h[t]);
    __syncthreads();
    if (n < N_NODES) {
        int wl = atomicAdd(&lc[d], 1);
        int w = basec[d] + wl;
        int r = nodeStart[d] + w;
        int eo = edgeStart[d] + w * d;
        perm[r] = n;
        eoffs[n] = eo;
        soffs[r] = eo;
    }
    if (n == 0) soffs[N_NODES] = N_EDGES;
}

// walk list, write entries sequentially into the node's sorted segment
__global__ void compact(const int* __restrict__ head, const int* __restrict__ nxt,
                        const int* __restrict__ src, const float* __restrict__ factor,
                        const int* __restrict__ eoffs, int2* __restrict__ entries) {
    int n = blockIdx.x * SCAN_BLK + threadIdx.x;
    if (n >= N_NODES) return;
    int o = eoffs[n];
    int p = head[n];
    while (p >= 0) {
        entries[o++] = make_int2(src[p], __float_as_int(factor[p]));
        p = nxt[p];
    }
}

// ---------------- W pre-swizzle: B-fragments for mfma_f32_16x16x32_bf16 ----------------

__global__ void swizzle_W(const float* __restrict__ W, uint4* __restrict__ bsw) {
    int idx = blockIdx.x * blockDim.x + threadIdx.x;
    if (idx >= 18 * 64) return;
    int t = idx >> 6, lane = idx & 63;
    int kt = t / 6, jt = t % 6;
    int quad = lane >> 4, l16 = lane & 15;
    const float4* wp = (const float4*)(W + (size_t)(jt * 16 + l16) * DIM + kt * 32 + quad * 8);
    float4 w0 = wp[0], w1 = wp[1];
    bsw[idx] = make_uint4(pack2bf(w0.x, w0.y), pack2bf(w0.z, w0.w),
                          pack2bf(w1.x, w1.y), pack2bf(w1.z, w1.w));
}

// ---------------- MFMA GEMM:  out[n][j] = bf16((X@W^T + b)[n][j] * norm[n]) ----------------

#define TILE_SH 104   // shorts per LDS tile row

template <typename T>
__global__ __launch_bounds__(256) void gemm_mfma(const T* __restrict__ X,
                                                 const uint4* __restrict__ bsw,
                                                 const float* __restrict__ bias,
                                                 const float* __restrict__ norm,
                                                 unsigned short* __restrict__ out) {
    __shared__ unsigned short tile[4][16 * TILE_SH];   // 13.3 KB
    int tid = threadIdx.x;
    int wave = tid >> 6, lane = tid & 63;
    int quad = lane >> 4, l16 = lane & 15;
    int n0 = blockIdx.x * 64 + wave * 16;
    int rowc = min(n0 + l16, N_NODES - 1);

    uint4 bfr[18];
#pragma unroll
    for (int t = 0; t < 18; ++t) bfr[t] = bsw[t * 64 + lane];

    v4f acc[6];
#pragma unroll
    for (int jt = 0; jt < 6; ++jt) acc[jt] = (v4f)(0.0f);

#pragma unroll
    for (int kt = 0; kt < 3; ++kt) {
        U4S8 a;
        if constexpr (std::is_same_v<T, float>) {
            const float4* xp = (const float4*)(X + (size_t)rowc * DIM + kt * 32 + quad * 8);
            float4 x0 = xp[0], x1 = xp[1];
            a.u = make_uint4(pack2bf(x0.x, x0.y), pack2bf(x0.z, x0.w),
                             pack2bf(x1.x, x1.y), pack2bf(x1.z, x1.w));
        } else {
            a.u = *(const uint4*)(X + (size_t)rowc * DIM + kt * 32 + quad * 8);
        }
#pragma unroll
        for (int jt = 0; jt < 6; ++jt) {
            U4S8 bb; bb.u = bfr[kt * 6 + jt];
            acc[jt] = __builtin_amdgcn_mfma_f32_16x16x32_bf16(a.s, bb.s, acc[jt], 0, 0, 0);
        }
    }

    float nm[4];
#pragma unroll
    for (int r = 0; r < 4; ++r) nm[r] = norm[min(n0 + quad * 4 + r, N_NODES - 1)];
#pragma unroll
    for (int jt = 0; jt < 6; ++jt) {
        float bj = bias[jt * 16 + l16];
#pragma unroll
        for (int r = 0; r < 4; ++r) {
            float v = (acc[jt][r] + bj) * nm[r];
            tile[wave][(quad * 4 + r) * TILE_SH + jt * 16 + l16] = f2bf(v);
        }
    }
    __builtin_amdgcn_s_waitcnt(0);   // drain lgkm before wave-local reads
#pragma unroll
    for (int i = 0; i < 3; ++i) {
        int chunk = lane + 64 * i;        // 0..191 = 16 rows x 12 uint4
        int rr = chunk / 12, cc = chunk - rr * 12;
        int gn = n0 + rr;
        if (gn < N_NODES) {
            uint4 v = *(uint4*)&tile[wave][rr * TILE_SH + cc * 8];
            *(uint4*)(out + (size_t)gn * DIM + cc * 8) = v;
        }
    }
}

// ---------------- gather aggregation: degree-sorted ranks, LDS entries, x4 ----------------

template <bool DO_TANH, bool POOL>
__global__ void gather_agg_bf16(const unsigned short* __restrict__ feat,
                                const int* __restrict__ soffs,
                                const int* __restrict__ perm,
                                const int2* __restrict__ entries,
                                unsigned short* __restrict__ out,
                                float* __restrict__ partials) {
    __shared__ int2 ents[CAP];       // 6 KB
    __shared__ float pool[DIM];
    __shared__ int sh_base, sh_cnt;
    int tid = threadIdx.x;
    int r0 = blockIdx.x * NPB;
    int r1 = min(r0 + NPB, N_NODES);
    if (POOL && tid < DIM) pool[tid] = 0.f;
    if (tid == 0) { sh_base = soffs[r0]; sh_cnt = soffs[r1] - sh_base; }
    __syncthreads();
    int base = sh_base, cnt = sh_cnt;

    int nl = tid / BCH;
    int c  = tid - nl * BCH;
    int rk = r0 + nl;
    bool active = (tid < NPB * BCH) && (rk < N_NODES);
    int lb = 0, le = 0;
    if (active) { lb = soffs[rk] - base; le = soffs[rk + 1] - base; }

    float a0[8], a1[8];
#pragma unroll
    for (int i = 0; i < 8; ++i) { a0[i] = 0.f; a1[i] = 0.f; }

    for (int tb = 0; tb < cnt; tb += CAP) {
        int tcnt = min(cnt - tb, CAP);
        if (tb) __syncthreads();
        for (int i = tid; i < tcnt; i += 256) ents[i] = entries[base + tb + i];
        __syncthreads();
        int s = max(lb - tb, 0), e = min(le - tb, tcnt);
        int p = s;
        for (; p + 3 < e; p += 4) {
            int2 e0 = ents[p], e1 = ents[p + 1], e2 = ents[p + 2], e3 = ents[p + 3];
            uint4 v0 = *((const uint4*)(feat + (size_t)e0.x * DIM) + c);
            uint4 v1 = *((const uint4*)(feat + (size_t)e1.x * DIM) + c);
            uint4 v2 = *((const uint4*)(feat + (size_t)e2.x * DIM) + c);
            uint4 v3 = *((const uint4*)(feat + (size_t)e3.x * DIM) + c);
            acc8(a0, v0, __int_as_float(e0.y));
            acc8(a1, v1, __int_as_float(e1.y));
            acc8(a0, v2, __int_as_float(e2.y));
            acc8(a1, v3, __int_as_float(e3.y));
        }
        for (; p < e; ++p) {
            int2 e0 = ents[p];
            uint4 v0 = *((const uint4*)(feat + (size_t)e0.x * DIM) + c);
            acc8(a0, v0, __int_as_float(e0.y));
        }
    }

#pragma unroll
    for (int i = 0; i < 8; ++i) a0[i] += a1[i];
    if (DO_TANH || POOL) {
#pragma unroll
        for (int i = 0; i < 8; ++i) a0[i] = fast_tanh(a0[i]);
    }
    if (!POOL) {
        if (active) {
            int n_out = perm[rk];
            uint4 o;
            o.x = pack2bf(a0[0], a0[1]);
            o.y = pack2bf(a0[2], a0[3]);
            o.z = pack2bf(a0[4], a0[5]);
            o.w = pack2bf(a0[6], a0[7]);
            ((uint4*)out)[n_out * BCH + c] = o;
        }
    } else {
        if (active) {
#pragma unroll
            for (int i = 0; i < 8; ++i) atomicAdd(&pool[c * 8 + i], a0[i]);
        }
        __syncthreads();
        if (tid < DIM) partials[(size_t)blockIdx.x * DIM + tid] = pool[tid];
    }
}

// ---------------- two-stage pooled reduce ----------------

__global__ void reduce_stage1(const float* __restrict__ poolpart, float* __restrict__ stage1) {
    __shared__ float pool[DIM];
    int b = blockIdx.x, t = threadIdx.x;
    if (t < DIM) pool[t] = 0.f;
    __syncthreads();
    const int base = b * R1_ROWS * DIM;
    float loc = 0.f;
    int lastc = -1;
    for (int i = t; i < R1_ROWS * DIM; i += 256) {
        int gi = base + i;
        if (gi < NBG * DIM) {
            int col = i % DIM;
            if (col != lastc) {
                if (lastc >= 0) atomicAdd(&pool[lastc], loc);
                lastc = col; loc = 0.f;
            }
            loc += poolpart[gi];
        }
    }
    if (lastc >= 0) atomicAdd(&pool[lastc], loc);
    __syncthreads();
    if (t < DIM) stage1[b * DIM + t] = pool[t];
}

__global__ void reduce_stage2(const float* __restrict__ stage1, float* __restrict__ out) {
    __shared__ float sm[960];
    int t = threadIdx.x;
    int col = t % DIM, slice = t / DIM;
    float s = 0.f;
    for (int k = slice; k < R1_BLOCKS; k += 10) s += stage1[k * DIM + col];
    sm[t] = s;
    __syncthreads();
    if (t < DIM) {
        float tot = 0.f;
#pragma unroll
        for (int i = 0; i < 10; ++i) tot += sm[i * DIM + t];
        out[t] = tanhf(tot * (1.0f / N_NODES));
    }
}

// ---------------- launch ----------------

extern "C" void kernel_launch(void* const* d_in, const int* in_sizes, int n_in,
                              void* d_out, int out_size, void* d_ws, size_t ws_size,
                              hipStream_t stream) {
    const float* inputs = (const float*)d_in[0];
    const float* W1     = (const float*)d_in[1];
    const float* b1     = (const float*)d_in[2];
    const float* W2     = (const float*)d_in[3];
    const float* b2     = (const float*)d_in[4];
    const float* factor = (const float*)d_in[5];
    const int*   src    = (const int*)d_in[6];
    const int*   dst    = (const int*)d_in[7];
    float* out = (float*)d_out;

    char* ws = (char*)d_ws;
    int*            head      = (int*)(ws + 0);              // 200 KB
    int*            nxt       = (int*)(ws + 262144);         // 3.2 MB
    int*            deg       = (int*)(ws + 3670016);        // 200 KB
    int*            soffs     = (int*)(ws + 3932160);        // 200 KB (+1)
    float*          norm      = (float*)(ws + 4194304);      // 200 KB
    int*            bins      = (int*)(ws + 4456448);        // 1 KB
    int*            nodeStart = (int*)(ws + 4457472);        // 1 KB
    int*            edgeStart = (int*)(ws + 4458496);        // 1 KB
    int*            binCursor = (int*)(ws + 4459520);        // 1 KB
    int2*           entries   = (int2*)(ws + 4718592);       // 6.4 MB
    unsigned short* bufA      = (unsigned short*)(ws + 11534336);  // 9.6 MB bf16 feat
    unsigned short* bufB      = (unsigned short*)(ws + 21364736);  // 9.6 MB bf16 feat
    float*          poolpart  = (float*)(ws + 31195136);     // 914 KB (NBG x 96)
    float*          stage1    = (float*)(ws + 32145536);     // 38.4 KB
    uint4*          bsw1      = (uint4*)(ws + 33554432);     // 18 KB W1 fragments
    uint4*          bsw2      = (uint4*)(ws + 33574912);     // 18 KB W2 fragments
    int*            perm      = (int*)(ws + 33595392);       // 200 KB
    int*            eoffs     = (int*)(ws + 33857536);       // 200 KB

    // W fragment pre-swizzle (independent of CSR build)
    swizzle_W<<<5, 256, 0, stream>>>(W1, bsw1);
    swizzle_W<<<5, 256, 0, stream>>>(W2, bsw2);

    // linked-list CSR build with degree-sorted placement
    hipMemsetAsync(head, 0xFF, N_NODES * sizeof(int), stream);
    hipMemsetAsync(bins, 0, NBINS * sizeof(int), stream);
    link_edges<<<(N_EDGES + 255) / 256, 256, 0, stream>>>(dst, head, nxt);
    walk_count_hist<<<NBLK, SCAN_BLK, 0, stream>>>(head, nxt, deg, norm, bins);
    bin_scan<<<1, NBINS, 0, stream>>>(bins, nodeStart, edgeStart, binCursor);
    rank_assign<<<NBLK, SCAN_BLK, 0, stream>>>(deg, nodeStart, edgeStart, binCursor,
                                               perm, eoffs, soffs);
    compact<<<NBLK, SCAN_BLK, 0, stream>>>(head, nxt, src, factor, eoffs, entries);

    const int GEMM_BLOCKS = (N_NODES + 63) / 64;   // 782

    // layer 1
    gemm_mfma<float><<<GEMM_BLOCKS, 256, 0, stream>>>(inputs, bsw1, b1, norm, bufA);
    gather_agg_bf16<true, false><<<NBG, 256, 0, stream>>>(bufA, soffs, perm, entries,
                                                          bufB, nullptr);

    // layer 2 (gather fuses tanh + column pooling, no feature write)
    gemm_mfma<unsigned short><<<GEMM_BLOCKS, 256, 0, stream>>>(bufB, bsw2, b2, norm, bufA);
    gather_agg_bf16<false, true><<<NBG, 256, 0, stream>>>(bufA, soffs, perm, entries,
                                                          nullptr, poolpart);

    // two-stage pooled reduce -> out
    reduce_stage1<<<R1_BLOCKS, 256, 0, stream>>>(poolpart, stage1);
    reduce_stage2<<<1, 960, 0, stream>>>(stage1, out);
}